// Round 4
// baseline (721.018 us; speedup 1.0000x reference)
//
#include <hip/hip_runtime.h>
#include <math.h>

#define NG 100000
#define ND 50000
#define NTOT 150000
#define DIM 128
#define NE 800000
#define EPSN 1e-12f

#define NBT_D 391  // ceil(ND/128)
#define NBT_G 782  // ceil(NG/128)

typedef __bf16 bf16x8 __attribute__((ext_vector_type(8)));
typedef float f32x4 __attribute__((ext_vector_type(4)));
typedef unsigned int uint32;

__device__ __forceinline__ ushort rne_bf16(float f) {
  uint32 u = __builtin_bit_cast(uint32, f);
  u += 0x7fffu + ((u >> 16) & 1u);
  return (ushort)(u >> 16);
}

// ---------------- unified CSR build (disease dsts rows [0,ND), gene dsts [ND,NTOT)) --------

__global__ void zero_ints(int* __restrict__ p, int n) {
  int i = blockIdx.x * 256 + threadIdx.x;
  if (i < n) p[i] = 0;
}

__global__ void count_deg2(const int* __restrict__ dst_g2d, const int* __restrict__ dst_d2g,
                           int* __restrict__ deg) {
  int i = blockIdx.x * 256 + threadIdx.x;
  if (i < NE)
    atomicAdd(&deg[dst_g2d[i]], 1);
  else if (i < 2 * NE)
    atomicAdd(&deg[ND + dst_d2g[i - NE]], 1);
}

__global__ void block_partials(const int* __restrict__ deg, int* __restrict__ part, int n) {
  __shared__ int s[256];
  int i = blockIdx.x * 256 + threadIdx.x;
  s[threadIdx.x] = (i < n) ? deg[i] : 0;
  __syncthreads();
  for (int st = 128; st > 0; st >>= 1) {
    if (threadIdx.x < st) s[threadIdx.x] += s[threadIdx.x + st];
    __syncthreads();
  }
  if (threadIdx.x == 0) part[blockIdx.x] = s[0];
}

// single block, 1024 threads; exclusive scan of part[0..nb), nb <= 1024
__global__ void scan_partials(int* __restrict__ part, int nb) {
  __shared__ int s[1024];
  int t = threadIdx.x;
  s[t] = (t < nb) ? part[t] : 0;
  __syncthreads();
  for (int off = 1; off < 1024; off <<= 1) {
    int v = (t >= off) ? s[t - off] : 0;
    __syncthreads();
    s[t] += v;
    __syncthreads();
  }
  if (t < nb) part[t] = (t > 0) ? s[t - 1] : 0;
}

__global__ void finalize_scan(int* __restrict__ deg_cur, const int* __restrict__ part,
                              int* __restrict__ off, int n, int total) {
  __shared__ int s[256];
  int t = threadIdx.x;
  int i = blockIdx.x * 256 + t;
  int d = (i < n) ? deg_cur[i] : 0;
  s[t] = d;
  __syncthreads();
  for (int o = 1; o < 256; o <<= 1) {
    int v = (t >= o) ? s[t - o] : 0;
    __syncthreads();
    s[t] += v;
    __syncthreads();
  }
  int excl = s[t] - d + part[blockIdx.x];
  if (i < n) {
    off[i] = excl;
    deg_cur[i] = excl;
    if (i == n - 1) off[n] = total;
  }
}

__global__ void fill_csr2(const int* __restrict__ src_g2d, const int* __restrict__ dst_g2d,
                          const int* __restrict__ src_d2g, const int* __restrict__ dst_d2g,
                          int* __restrict__ cur, int* __restrict__ csr) {
  int i = blockIdx.x * 256 + threadIdx.x;
  if (i < NE) {
    int p = atomicAdd(&cur[dst_g2d[i]], 1);
    csr[p] = src_g2d[i];
  } else if (i < 2 * NE) {
    int p = atomicAdd(&cur[ND + dst_d2g[i - NE]], 1);
    csr[p] = src_d2g[i - NE];
  }
}

// ---------------- fp32 -> bf16 table convert (RNE), both tables in one launch ------------

__global__ void to_bf16_all(const float* __restrict__ xg, const float* __restrict__ xd,
                            ushort* __restrict__ yg, ushort* __restrict__ yd) {
  int i = blockIdx.x * 256 + threadIdx.x;  // over NTOT*16 8-elem units
  if (i >= NTOT * 16) return;
  const float* x;
  ushort* y;
  int j;
  if (i < NG * 16) {
    x = xg; y = yg; j = i;
  } else {
    x = xd; y = yd; j = i - NG * 16;
  }
  const float4* px = (const float4*)x;
  float4 a = px[2 * j], b = px[2 * j + 1];
  float v[8] = {a.x, a.y, a.z, a.w, b.x, b.y, b.z, b.w};
  uint32 u[4];
#pragma unroll
  for (int k = 0; k < 4; k++)
    u[k] = (uint32)rne_bf16(v[2 * k]) | ((uint32)rne_bf16(v[2 * k + 1]) << 16);
  ((int4*)y)[j] = make_int4((int)u[0], (int)u[1], (int)u[2], (int)u[3]);
}

// ---------------- W pre-split: fp32 -> bf16 hi (trunc) + bf16 lo (residual) --------------

__global__ void split_w(const float* __restrict__ Wl, const float* __restrict__ Wr,
                        ushort* __restrict__ WlH, ushort* __restrict__ WlL,
                        ushort* __restrict__ WrH, ushort* __restrict__ WrL) {
  int i = blockIdx.x * 256 + threadIdx.x;
  if (i >= 4 * 128 * 128) return;
  {
    float a = Wl[i];
    uint32 u = __builtin_bit_cast(uint32, a);
    float hf = __builtin_bit_cast(float, u & 0xffff0000u);
    WlH[i] = (ushort)(u >> 16);
    WlL[i] = (ushort)(__builtin_bit_cast(uint32, a - hf) >> 16);
  }
  {
    float a = Wr[i];
    uint32 u = __builtin_bit_cast(uint32, a);
    float hf = __builtin_bit_cast(float, u & 0xffff0000u);
    WrH[i] = (ushort)(u >> 16);
    WrL[i] = (ushort)(__builtin_bit_cast(uint32, a - hf) >> 16);
  }
}

// ---------------- mean aggregation over bf16 rows, unified node space --------------------

__device__ __forceinline__ void acc8(float* a, int4 u) {
  uint32 w;
  w = (uint32)u.x;
  a[0] += __builtin_bit_cast(float, w << 16);
  a[1] += __builtin_bit_cast(float, w & 0xffff0000u);
  w = (uint32)u.y;
  a[2] += __builtin_bit_cast(float, w << 16);
  a[3] += __builtin_bit_cast(float, w & 0xffff0000u);
  w = (uint32)u.z;
  a[4] += __builtin_bit_cast(float, w << 16);
  a[5] += __builtin_bit_cast(float, w & 0xffff0000u);
  w = (uint32)u.w;
  a[6] += __builtin_bit_cast(float, w << 16);
  a[7] += __builtin_bit_cast(float, w & 0xffff0000u);
}

__global__ void agg_comb(const ushort* __restrict__ xg_bf, const ushort* __restrict__ xd_bf,
                         const int* __restrict__ off, const int* __restrict__ csr,
                         ushort* __restrict__ agg_bf) {
  int node = (blockIdx.x * 256 + threadIdx.x) >> 6;
  if (node >= NTOT) return;
  int lane = threadIdx.x & 63;
  const ushort* xsrc = (node < ND) ? xg_bf : xd_bf;  // disease dsts gather genes & v.v.
  int e0 = off[node], e1 = off[node + 1];
  int q = lane >> 4, l16 = lane & 15;
  const int4* xs = (const int4*)xsrc;
  float a[8] = {0.f, 0.f, 0.f, 0.f, 0.f, 0.f, 0.f, 0.f};
  int e = e0 + q;
  for (; e + 4 < e1; e += 8) {
    int s0 = csr[e], s1 = csr[e + 4];
    int4 u = xs[(size_t)s0 * 16 + l16];
    int4 v = xs[(size_t)s1 * 16 + l16];
    acc8(a, u);
    acc8(a, v);
  }
  if (e < e1) acc8(a, xs[(size_t)csr[e] * 16 + l16]);
#pragma unroll
  for (int j = 0; j < 8; j++) {
    a[j] += __shfl_xor(a[j], 16);
    a[j] += __shfl_xor(a[j], 32);
  }
  if (q == 0) {
    int deg = e1 - e0;
    float inv = (deg > 0) ? 1.f / (float)deg : 0.f;
    uint32 u[4];
#pragma unroll
    for (int j = 0; j < 4; j++)
      u[j] = (uint32)rne_bf16(a[2 * j] * inv) | ((uint32)rne_bf16(a[2 * j + 1] * inv) << 16);
    *(int4*)&agg_bf[(size_t)node * DIM + l16 * 8] =
        make_int4((int)u[0], (int)u[1], (int)u[2], (int)u[3]);
  }
}

// ---------------- MFMA SAGE update, fully-coalesced staging + epilogue -------------------
// Block: 128 rows x 128 cols, 4 waves. C = agg*Wl^T (bf16, hi+lo W) + X*Wr^T (split-bf16 X,
// hi+lo W, 3 terms). A operands staged via LDS with coalesced global loads; epilogue goes
// through a per-wave LDS tile -> coalesced dwordx4 stores + float4 skip-add reads.

__launch_bounds__(256)
__global__ void sage_dual(const ushort* __restrict__ agg_bf, const float* __restrict__ xd,
                          const float* __restrict__ xg, const ushort* __restrict__ WlH,
                          const ushort* __restrict__ WlL, const ushort* __restrict__ WrH,
                          const ushort* __restrict__ WrL, const float* __restrict__ bias_all,
                          float* __restrict__ outd, float* __restrict__ outg,
                          ushort* __restrict__ xbf_d, ushort* __restrict__ xbf_g, int layer,
                          int relu, int write_bf) {
  __shared__ __align__(16) char smem[40960];
  ushort* sW = (ushort*)smem;            // [2 planes][128][40] = 20480 B (hi/lo of current W)
  ushort* sA = (ushort*)(smem + 20480);  // [2 planes][128][40] (ph0: agg in plane0; ph1: x hi/lo)

  int b = blockIdx.x;
  const float* X;
  float* O;
  ushort* OBF;
  int n, set, r0g, cbase;
  if (b < NBT_D) {
    X = xd; O = outd; OBF = xbf_d; n = ND; set = layer * 2; r0g = b * 128; cbase = 0;
  } else {
    X = xg; O = outg; OBF = xbf_g; n = NG; set = layer * 2 + 1;
    r0g = (b - NBT_D) * 128; cbase = ND;
  }
  const ushort* WH[2] = {WlH + set * 16384, WrH + set * 16384};
  const ushort* WL[2] = {WlL + set * 16384, WrL + set * 16384};
  const float* bias = bias_all + set * 128;

  int tid = threadIdx.x;
  int wave = tid >> 6, lane = tid & 63;
  int m = lane & 15, q = lane >> 4;

  f32x4 acc[2][8];
#pragma unroll
  for (int mt = 0; mt < 2; mt++)
#pragma unroll
    for (int nt = 0; nt < 8; nt++) acc[mt][nt] = (f32x4)0.f;

  int arow0 = wave * 32 + m;  // mt0 row (block-local)
  int arow1 = arow0 + 16;     // mt1 row

#pragma unroll
  for (int ph = 0; ph < 2; ph++) {
#pragma unroll
    for (int ks = 0; ks < 4; ks++) {
      int k0 = ks * 32;
      // ---- issue coalesced global loads ----
      int4 wv[4];
#pragma unroll
      for (int i = 0; i < 4; i++) {
        int u = tid + i * 256;  // 1024 units: [plane][n(128)][piece(4)] of 16B
        int pl = u >> 9, idx = u & 511, wn = idx >> 2, wp = idx & 3;
        const ushort* base = pl ? WL[ph] : WH[ph];
        wv[i] = *(const int4*)&base[wn * 128 + k0 + wp * 8];
      }
      int4 av[2];
      float4 xv[4];
      if (ph == 0) {
#pragma unroll
        for (int i = 0; i < 2; i++) {
          int u = tid + i * 256;  // 512 units: [n(128)][piece(4)] of 16B bf16
          int an = u >> 2, ap = u & 3;
          int rg = r0g + an;
          if (rg >= n) rg = n - 1;
          av[i] = *(const int4*)&agg_bf[(size_t)(cbase + rg) * DIM + k0 + ap * 8];
        }
      } else {
#pragma unroll
        for (int i = 0; i < 4; i++) {
          int u = tid + i * 256;  // 1024 units: [n(128)][piece(8)] of 16B fp32
          int xn = u >> 3, xp = u & 7;
          int rg = r0g + xn;
          if (rg >= n) rg = n - 1;
          xv[i] = *(const float4*)&X[(size_t)rg * DIM + k0 + xp * 4];
        }
      }
      __syncthreads();  // previous chunk's LDS reads done
      // ---- LDS writes ----
#pragma unroll
      for (int i = 0; i < 4; i++) {
        int u = tid + i * 256;
        int pl = u >> 9, idx = u & 511, wn = idx >> 2, wp = idx & 3;
        *(int4*)&sW[pl * 5120 + wn * 40 + wp * 8] = wv[i];
      }
      if (ph == 0) {
#pragma unroll
        for (int i = 0; i < 2; i++) {
          int u = tid + i * 256;
          int an = u >> 2, ap = u & 3;
          *(int4*)&sA[an * 40 + ap * 8] = av[i];
        }
      } else {
#pragma unroll
        for (int i = 0; i < 4; i++) {
          int u = tid + i * 256;
          int xn = u >> 3, xp = u & 7;
          float v[4] = {xv[i].x, xv[i].y, xv[i].z, xv[i].w};
          ushort h[4], l[4];
#pragma unroll
          for (int j = 0; j < 4; j++) {
            uint32 uu = __builtin_bit_cast(uint32, v[j]);
            h[j] = (ushort)(uu >> 16);
            float hf = __builtin_bit_cast(float, uu & 0xffff0000u);
            l[j] = (ushort)(__builtin_bit_cast(uint32, v[j] - hf) >> 16);
          }
          int2 hp = make_int2((int)((uint32)h[0] | ((uint32)h[1] << 16)),
                              (int)((uint32)h[2] | ((uint32)h[3] << 16)));
          int2 lp = make_int2((int)((uint32)l[0] | ((uint32)l[1] << 16)),
                              (int)((uint32)l[2] | ((uint32)l[3] << 16)));
          *(int2*)&sA[xn * 40 + xp * 4] = hp;
          *(int2*)&sA[5120 + xn * 40 + xp * 4] = lp;
        }
      }
      __syncthreads();
      // ---- fragments + MFMA ----
      if (ph == 0) {
        bf16x8 a0 = __builtin_bit_cast(bf16x8, *(const int4*)&sA[arow0 * 40 + q * 8]);
        bf16x8 a1 = __builtin_bit_cast(bf16x8, *(const int4*)&sA[arow1 * 40 + q * 8]);
#pragma unroll
        for (int nt = 0; nt < 8; nt++) {
          int nn = nt * 16 + m;
          bf16x8 bh = __builtin_bit_cast(bf16x8, *(const int4*)&sW[nn * 40 + q * 8]);
          bf16x8 bl = __builtin_bit_cast(bf16x8, *(const int4*)&sW[5120 + nn * 40 + q * 8]);
          acc[0][nt] = __builtin_amdgcn_mfma_f32_16x16x32_bf16(a0, bh, acc[0][nt], 0, 0, 0);
          acc[1][nt] = __builtin_amdgcn_mfma_f32_16x16x32_bf16(a1, bh, acc[1][nt], 0, 0, 0);
          acc[0][nt] = __builtin_amdgcn_mfma_f32_16x16x32_bf16(a0, bl, acc[0][nt], 0, 0, 0);
          acc[1][nt] = __builtin_amdgcn_mfma_f32_16x16x32_bf16(a1, bl, acc[1][nt], 0, 0, 0);
        }
      } else {
        bf16x8 ah0 = __builtin_bit_cast(bf16x8, *(const int4*)&sA[arow0 * 40 + q * 8]);
        bf16x8 ah1 = __builtin_bit_cast(bf16x8, *(const int4*)&sA[arow1 * 40 + q * 8]);
        bf16x8 al0 = __builtin_bit_cast(bf16x8, *(const int4*)&sA[5120 + arow0 * 40 + q * 8]);
        bf16x8 al1 = __builtin_bit_cast(bf16x8, *(const int4*)&sA[5120 + arow1 * 40 + q * 8]);
#pragma unroll
        for (int nt = 0; nt < 8; nt++) {
          int nn = nt * 16 + m;
          bf16x8 bh = __builtin_bit_cast(bf16x8, *(const int4*)&sW[nn * 40 + q * 8]);
          bf16x8 bl = __builtin_bit_cast(bf16x8, *(const int4*)&sW[5120 + nn * 40 + q * 8]);
          acc[0][nt] = __builtin_amdgcn_mfma_f32_16x16x32_bf16(ah0, bh, acc[0][nt], 0, 0, 0);
          acc[1][nt] = __builtin_amdgcn_mfma_f32_16x16x32_bf16(ah1, bh, acc[1][nt], 0, 0, 0);
          acc[0][nt] = __builtin_amdgcn_mfma_f32_16x16x32_bf16(ah0, bl, acc[0][nt], 0, 0, 0);
          acc[1][nt] = __builtin_amdgcn_mfma_f32_16x16x32_bf16(ah1, bl, acc[1][nt], 0, 0, 0);
          acc[0][nt] = __builtin_amdgcn_mfma_f32_16x16x32_bf16(al0, bh, acc[0][nt], 0, 0, 0);
          acc[1][nt] = __builtin_amdgcn_mfma_f32_16x16x32_bf16(al1, bh, acc[1][nt], 0, 0, 0);
        }
      }
    }
  }
  __syncthreads();  // all waves done with sW/sA before LDS reuse

  // ---- epilogue via per-wave LDS tile (16 rows x 132 cols fp32 per mt-half) ----
  float bb[8];
#pragma unroll
  for (int nt = 0; nt < 8; nt++) bb[nt] = bias[nt * 16 + m];

  const int S = 132;
  float* wbuf = (float*)smem + wave * (16 * S);  // 8448 B per wave, 33792 B total

  int half = lane >> 5;    // row parity for readback
  int c4 = (lane & 31) * 4;  // col quad for readback

#pragma unroll
  for (int mt = 0; mt < 2; mt++) {
    // normalized h -> LDS (wave-lockstep; no barrier needed, wave-private region)
#pragma unroll
    for (int reg = 0; reg < 4; reg++) {
      float h[8];
      float ss = 0.f;
#pragma unroll
      for (int nt = 0; nt < 8; nt++) {
        float v = acc[mt][nt][reg] + bb[nt];
        if (relu) v = fmaxf(v, 0.f);
        h[nt] = v;
        ss += v * v;
      }
      ss += __shfl_xor(ss, 1);
      ss += __shfl_xor(ss, 2);
      ss += __shfl_xor(ss, 4);
      ss += __shfl_xor(ss, 8);
      float inv = 1.f / fmaxf(sqrtf(ss), EPSN);
      int rrel = q * 4 + reg;  // 0..15
#pragma unroll
      for (int nt = 0; nt < 8; nt++) wbuf[rrel * S + nt * 16 + m] = h[nt] * inv;
    }
    // coalesced readback + skip-add + store (2 rows per iteration)
#pragma unroll
    for (int i = 0; i < 8; i++) {
      int rrel = i * 2 + half;
      int R = r0g + wave * 32 + mt * 16 + rrel;
      if (R < n) {
        f32x4 hv = *(const f32x4*)&wbuf[rrel * S + c4];
        float4 xr = *(const float4*)&X[(size_t)R * DIM + c4];
        float4 o;
        o.x = hv[0] + xr.x;
        o.y = hv[1] + xr.y;
        o.z = hv[2] + xr.z;
        o.w = hv[3] + xr.w;
        *(float4*)&O[(size_t)R * DIM + c4] = o;
        if (write_bf) {
          int2 pk = make_int2((int)((uint32)rne_bf16(o.x) | ((uint32)rne_bf16(o.y) << 16)),
                              (int)((uint32)rne_bf16(o.z) | ((uint32)rne_bf16(o.w) << 16)));
          *(int2*)&OBF[(size_t)R * DIM + c4] = pk;
        }
      }
    }
  }
}

// ---------------- launch ----------------

extern "C" void kernel_launch(void* const* d_in, const int* in_sizes, int n_in,
                              void* d_out, int out_size, void* d_ws, size_t ws_size,
                              hipStream_t stream) {
  const float* xg0 = (const float*)d_in[0];
  const float* xd0 = (const float*)d_in[1];
  const float* Wl = (const float*)d_in[2];
  const float* Wr = (const float*)d_in[3];
  const float* bs = (const float*)d_in[4];
  const int* src_g2d = (const int*)d_in[5];
  const int* dst_g2d = (const int*)d_in[6];
  const int* src_d2g = (const int*)d_in[7];
  const int* dst_d2g = (const int*)d_in[8];

  float* out_xg = (float*)d_out;
  float* out_xd = (float*)d_out + (size_t)NG * DIM;

  char* p = (char*)d_ws;
  auto alloc = [&](size_t bytes) -> char* {
    char* q = p;
    p += (bytes + 255) & ~(size_t)255;
    return q;
  };
  int* off = (int*)alloc((NTOT + 1) * 4);
  int* cur = (int*)alloc((size_t)NTOT * 4);
  int* part = (int*)alloc(1024 * 4);
  int* csr = (int*)alloc((size_t)2 * NE * 4);
  ushort* agg_bf = (ushort*)alloc((size_t)NTOT * DIM * 2);
  ushort* xg_bf = (ushort*)alloc((size_t)NG * DIM * 2);
  ushort* xd_bf = (ushort*)alloc((size_t)ND * DIM * 2);
  ushort* WlH = (ushort*)alloc((size_t)4 * 128 * 128 * 2);
  ushort* WlL = (ushort*)alloc((size_t)4 * 128 * 128 * 2);
  ushort* WrH = (ushort*)alloc((size_t)4 * 128 * 128 * 2);
  ushort* WrL = (ushort*)alloc((size_t)4 * 128 * 128 * 2);

  const int TB = 256;
  int nbN = (NTOT + TB - 1) / TB;      // 586
  int nbE2 = (2 * NE + TB - 1) / TB;   // 6250

  split_w<<<256, TB, 0, stream>>>(Wl, Wr, WlH, WlL, WrH, WrL);
  to_bf16_all<<<(NTOT * 16 + TB - 1) / TB, TB, 0, stream>>>(xg0, xd0, xg_bf, xd_bf);

  zero_ints<<<nbN, TB, 0, stream>>>(cur, NTOT);
  count_deg2<<<nbE2, TB, 0, stream>>>(dst_g2d, dst_d2g, cur);
  block_partials<<<nbN, TB, 0, stream>>>(cur, part, NTOT);
  scan_partials<<<1, 1024, 0, stream>>>(part, nbN);
  finalize_scan<<<nbN, TB, 0, stream>>>(cur, part, off, NTOT, 2 * NE);
  fill_csr2<<<nbE2, TB, 0, stream>>>(src_g2d, dst_g2d, src_d2g, dst_d2g, cur, csr);

  int aggBlocks = NTOT / 4;        // 37500 (one wave per dst node)
  int sageBlocks = NBT_D + NBT_G;  // 1173

  // layer 0 (relu); sage also emits bf16 copy of out for layer-1 gather
  agg_comb<<<aggBlocks, TB, 0, stream>>>(xg_bf, xd_bf, off, csr, agg_bf);
  sage_dual<<<sageBlocks, TB, 0, stream>>>(agg_bf, xd0, xg0, WlH, WlL, WrH, WrL, bs, out_xd,
                                           out_xg, xd_bf, xg_bf, 0, 1, 1);

  // layer 1 (no relu), in-place on d_out
  agg_comb<<<aggBlocks, TB, 0, stream>>>(xg_bf, xd_bf, off, csr, agg_bf);
  sage_dual<<<sageBlocks, TB, 0, stream>>>(agg_bf, out_xd, out_xg, WlH, WlL, WrH, WrL, bs,
                                           out_xd, out_xg, xd_bf, xg_bf, 1, 0, 0);
}

// Round 5
// 611.747 us; speedup vs baseline: 1.1786x; 1.1786x over previous
//
#include <hip/hip_runtime.h>
#include <math.h>

#define NG 100000
#define ND 50000
#define NTOT 150000
#define DIM 128
#define NE 800000
#define EPSN 1e-12f

#define NBT_D 391  // ceil(ND/128)
#define NBT_G 782  // ceil(NG/128)

#define NBK 586    // ceil(NTOT/256) buckets of 256 dst nodes
#define SCB 128    // scatter blocks
#define EPB 12500  // edges per scatter block = ceil(2*NE/SCB)

typedef __bf16 bf16x8 __attribute__((ext_vector_type(8)));
typedef float f32x4 __attribute__((ext_vector_type(4)));
typedef unsigned int uint32;

__device__ __forceinline__ ushort rne_bf16(float f) {
  uint32 u = __builtin_bit_cast(uint32, f);
  u += 0x7fffu + ((u >> 16) & 1u);
  return (ushort)(u >> 16);
}

// ---------------- bucketed CSR build ----------------
// unified dst space: disease dsts [0,ND), gene dsts [ND,NTOT). bucket = dst>>8.

__global__ void zero_ints(int* __restrict__ p, int n) {
  int i = blockIdx.x * 256 + threadIdx.x;
  if (i < n) p[i] = 0;
}

// Pass A1: per-bucket edge counts (LDS histogram -> few global atomics)
__global__ void bucket_count(const int* __restrict__ dst_g2d, const int* __restrict__ dst_d2g,
                             int* __restrict__ bcnt) {
  __shared__ int h[NBK];
  for (int j = threadIdx.x; j < NBK; j += 256) h[j] = 0;
  __syncthreads();
  int stride = gridDim.x * 256;
  for (int i = blockIdx.x * 256 + threadIdx.x; i < 2 * NE; i += stride) {
    int d = (i < NE) ? dst_g2d[i] : ND + dst_d2g[i - NE];
    atomicAdd(&h[d >> 8], 1);
  }
  __syncthreads();
  for (int j = threadIdx.x; j < NBK; j += 256)
    if (h[j]) atomicAdd(&bcnt[j], h[j]);
}

// Pass A2: exclusive scan of bucket counts; init cursors
__global__ void bucket_scan(const int* __restrict__ bcnt, int* __restrict__ bbase,
                            int* __restrict__ bcur) {
  __shared__ int s[1024];
  int t = threadIdx.x;
  s[t] = (t < NBK) ? bcnt[t] : 0;
  __syncthreads();
  for (int off = 1; off < 1024; off <<= 1) {
    int v = (t >= off) ? s[t - off] : 0;
    __syncthreads();
    s[t] += v;
    __syncthreads();
  }
  if (t < NBK) {
    int e = (t > 0) ? s[t - 1] : 0;
    bbase[t] = e;
    bcur[t] = e;
  }
  if (t == 0) bbase[NBK] = 2 * NE;
}

// Pass A3: scatter (dst,src) pairs into bucket segments. Each block claims contiguous
// per-bucket chunks (1 atomic per block x nonempty bucket) -> single-owner cache lines.
__global__ void bucket_scatter(const int* __restrict__ src_g2d, const int* __restrict__ dst_g2d,
                               const int* __restrict__ src_d2g, const int* __restrict__ dst_d2g,
                               int* __restrict__ bcur, int2* __restrict__ pairs) {
  __shared__ int h[NBK];
  __shared__ int base[NBK];
  int e0 = blockIdx.x * EPB;
  int e1 = e0 + EPB;
  if (e1 > 2 * NE) e1 = 2 * NE;
  for (int j = threadIdx.x; j < NBK; j += 256) h[j] = 0;
  __syncthreads();
  for (int i = e0 + threadIdx.x; i < e1; i += 256) {
    int d = (i < NE) ? dst_g2d[i] : ND + dst_d2g[i - NE];
    atomicAdd(&h[d >> 8], 1);
  }
  __syncthreads();
  for (int j = threadIdx.x; j < NBK; j += 256) {
    int c = h[j];
    base[j] = c ? atomicAdd(&bcur[j], c) : 0;
    h[j] = 0;  // reuse as local cursor
  }
  __syncthreads();
  for (int i = e0 + threadIdx.x; i < e1; i += 256) {
    int d, s;
    if (i < NE) {
      d = dst_g2d[i];
      s = src_g2d[i];
    } else {
      d = ND + dst_d2g[i - NE];
      s = src_d2g[i - NE];
    }
    int bkt = d >> 8;
    int p = base[bkt] + atomicAdd(&h[bkt], 1);
    pairs[p] = make_int2(d, s);
  }
}

// Pass B: one block per bucket. LDS count + scan -> off[] (coalesced) and csr placement
// within the block-private (L2-hot) segment.
__global__ void bucket_to_csr(const int* __restrict__ bbase, const int2* __restrict__ pairs,
                              int* __restrict__ off, int* __restrict__ csr) {
  __shared__ int cnt[256];
  __shared__ int ss[256];
  int b = blockIdx.x, t = threadIdx.x;
  int n0 = b << 8;
  int s0 = bbase[b], s1 = bbase[b + 1];
  cnt[t] = 0;
  __syncthreads();
  for (int i = s0 + t; i < s1; i += 256) atomicAdd(&cnt[pairs[i].x - n0], 1);
  __syncthreads();
  int x = cnt[t];
  ss[t] = x;
  __syncthreads();
  for (int o = 1; o < 256; o <<= 1) {
    int y = (t >= o) ? ss[t - o] : 0;
    __syncthreads();
    ss[t] += y;
    __syncthreads();
  }
  int abs0 = s0 + ss[t] - x;
  int node = n0 + t;
  if (node < NTOT) off[node] = abs0;
  if (node == NTOT - 1) off[NTOT] = 2 * NE;
  __syncthreads();
  cnt[t] = abs0;  // absolute cursor
  __syncthreads();
  for (int i = s0 + t; i < s1; i += 256) {
    int2 e = pairs[i];
    int p = atomicAdd(&cnt[e.x - n0], 1);
    csr[p] = e.y;
  }
}

// ---------------- fp32 -> bf16 table convert (RNE), both tables in one launch ------------

__global__ void to_bf16_all(const float* __restrict__ xg, const float* __restrict__ xd,
                            ushort* __restrict__ yg, ushort* __restrict__ yd) {
  int i = blockIdx.x * 256 + threadIdx.x;
  if (i >= NTOT * 16) return;
  const float* x;
  ushort* y;
  int j;
  if (i < NG * 16) {
    x = xg; y = yg; j = i;
  } else {
    x = xd; y = yd; j = i - NG * 16;
  }
  const float4* px = (const float4*)x;
  float4 a = px[2 * j], b = px[2 * j + 1];
  float v[8] = {a.x, a.y, a.z, a.w, b.x, b.y, b.z, b.w};
  uint32 u[4];
#pragma unroll
  for (int k = 0; k < 4; k++)
    u[k] = (uint32)rne_bf16(v[2 * k]) | ((uint32)rne_bf16(v[2 * k + 1]) << 16);
  ((int4*)y)[j] = make_int4((int)u[0], (int)u[1], (int)u[2], (int)u[3]);
}

// ---------------- W pre-split: fp32 -> bf16 hi (trunc) + bf16 lo (residual) --------------

__global__ void split_w(const float* __restrict__ Wl, const float* __restrict__ Wr,
                        ushort* __restrict__ WlH, ushort* __restrict__ WlL,
                        ushort* __restrict__ WrH, ushort* __restrict__ WrL) {
  int i = blockIdx.x * 256 + threadIdx.x;
  if (i >= 4 * 128 * 128) return;
  {
    float a = Wl[i];
    uint32 u = __builtin_bit_cast(uint32, a);
    float hf = __builtin_bit_cast(float, u & 0xffff0000u);
    WlH[i] = (ushort)(u >> 16);
    WlL[i] = (ushort)(__builtin_bit_cast(uint32, a - hf) >> 16);
  }
  {
    float a = Wr[i];
    uint32 u = __builtin_bit_cast(uint32, a);
    float hf = __builtin_bit_cast(float, u & 0xffff0000u);
    WrH[i] = (ushort)(u >> 16);
    WrL[i] = (ushort)(__builtin_bit_cast(uint32, a - hf) >> 16);
  }
}

// ---------------- mean aggregation over bf16 rows, unified node space --------------------

__device__ __forceinline__ void acc8(float* a, int4 u) {
  uint32 w;
  w = (uint32)u.x;
  a[0] += __builtin_bit_cast(float, w << 16);
  a[1] += __builtin_bit_cast(float, w & 0xffff0000u);
  w = (uint32)u.y;
  a[2] += __builtin_bit_cast(float, w << 16);
  a[3] += __builtin_bit_cast(float, w & 0xffff0000u);
  w = (uint32)u.z;
  a[4] += __builtin_bit_cast(float, w << 16);
  a[5] += __builtin_bit_cast(float, w & 0xffff0000u);
  w = (uint32)u.w;
  a[6] += __builtin_bit_cast(float, w << 16);
  a[7] += __builtin_bit_cast(float, w & 0xffff0000u);
}

__global__ void agg_comb(const ushort* __restrict__ xg_bf, const ushort* __restrict__ xd_bf,
                         const int* __restrict__ off, const int* __restrict__ csr,
                         ushort* __restrict__ agg_bf) {
  int node = (blockIdx.x * 256 + threadIdx.x) >> 6;
  if (node >= NTOT) return;
  int lane = threadIdx.x & 63;
  const ushort* xsrc = (node < ND) ? xg_bf : xd_bf;
  int e0 = off[node], e1 = off[node + 1];
  int q = lane >> 4, l16 = lane & 15;
  const int4* xs = (const int4*)xsrc;
  float a[8] = {0.f, 0.f, 0.f, 0.f, 0.f, 0.f, 0.f, 0.f};
  int e = e0 + q;
  for (; e + 4 < e1; e += 8) {
    int s0 = csr[e], s1 = csr[e + 4];
    int4 u = xs[(size_t)s0 * 16 + l16];
    int4 v = xs[(size_t)s1 * 16 + l16];
    acc8(a, u);
    acc8(a, v);
  }
  if (e < e1) acc8(a, xs[(size_t)csr[e] * 16 + l16]);
#pragma unroll
  for (int j = 0; j < 8; j++) {
    a[j] += __shfl_xor(a[j], 16);
    a[j] += __shfl_xor(a[j], 32);
  }
  if (q == 0) {
    int deg = e1 - e0;
    float inv = (deg > 0) ? 1.f / (float)deg : 0.f;
    uint32 u[4];
#pragma unroll
    for (int j = 0; j < 4; j++)
      u[j] = (uint32)rne_bf16(a[2 * j] * inv) | ((uint32)rne_bf16(a[2 * j + 1] * inv) << 16);
    *(int4*)&agg_bf[(size_t)node * DIM + l16 * 8] =
        make_int4((int)u[0], (int)u[1], (int)u[2], (int)u[3]);
  }
}

// ---------------- MFMA SAGE update, coalesced staging + epilogue -------------------------

__launch_bounds__(256)
__global__ void sage_dual(const ushort* __restrict__ agg_bf, const float* __restrict__ xd,
                          const float* __restrict__ xg, const ushort* __restrict__ WlH,
                          const ushort* __restrict__ WlL, const ushort* __restrict__ WrH,
                          const ushort* __restrict__ WrL, const float* __restrict__ bias_all,
                          float* __restrict__ outd, float* __restrict__ outg,
                          ushort* __restrict__ xbf_d, ushort* __restrict__ xbf_g, int layer,
                          int relu, int write_bf) {
  __shared__ __align__(16) char smem[40960];
  ushort* sW = (ushort*)smem;            // [2 planes][128][40]
  ushort* sA = (ushort*)(smem + 20480);  // [2 planes][128][40]

  int b = blockIdx.x;
  const float* X;
  float* O;
  ushort* OBF;
  int n, set, r0g, cbase;
  if (b < NBT_D) {
    X = xd; O = outd; OBF = xbf_d; n = ND; set = layer * 2; r0g = b * 128; cbase = 0;
  } else {
    X = xg; O = outg; OBF = xbf_g; n = NG; set = layer * 2 + 1;
    r0g = (b - NBT_D) * 128; cbase = ND;
  }
  const ushort* WH[2] = {WlH + set * 16384, WrH + set * 16384};
  const ushort* WL[2] = {WlL + set * 16384, WrL + set * 16384};
  const float* bias = bias_all + set * 128;

  int tid = threadIdx.x;
  int wave = tid >> 6, lane = tid & 63;
  int m = lane & 15, q = lane >> 4;

  f32x4 acc[2][8];
#pragma unroll
  for (int mt = 0; mt < 2; mt++)
#pragma unroll
    for (int nt = 0; nt < 8; nt++) acc[mt][nt] = (f32x4)0.f;

  int arow0 = wave * 32 + m;
  int arow1 = arow0 + 16;

#pragma unroll
  for (int ph = 0; ph < 2; ph++) {
#pragma unroll
    for (int ks = 0; ks < 4; ks++) {
      int k0 = ks * 32;
      int4 wv[4];
#pragma unroll
      for (int i = 0; i < 4; i++) {
        int u = tid + i * 256;
        int pl = u >> 9, idx = u & 511, wn = idx >> 2, wp = idx & 3;
        const ushort* base = pl ? WL[ph] : WH[ph];
        wv[i] = *(const int4*)&base[wn * 128 + k0 + wp * 8];
      }
      int4 av[2];
      float4 xv[4];
      if (ph == 0) {
#pragma unroll
        for (int i = 0; i < 2; i++) {
          int u = tid + i * 256;
          int an = u >> 2, ap = u & 3;
          int rg = r0g + an;
          if (rg >= n) rg = n - 1;
          av[i] = *(const int4*)&agg_bf[(size_t)(cbase + rg) * DIM + k0 + ap * 8];
        }
      } else {
#pragma unroll
        for (int i = 0; i < 4; i++) {
          int u = tid + i * 256;
          int xn = u >> 3, xp = u & 7;
          int rg = r0g + xn;
          if (rg >= n) rg = n - 1;
          xv[i] = *(const float4*)&X[(size_t)rg * DIM + k0 + xp * 4];
        }
      }
      __syncthreads();
#pragma unroll
      for (int i = 0; i < 4; i++) {
        int u = tid + i * 256;
        int pl = u >> 9, idx = u & 511, wn = idx >> 2, wp = idx & 3;
        *(int4*)&sW[pl * 5120 + wn * 40 + wp * 8] = wv[i];
      }
      if (ph == 0) {
#pragma unroll
        for (int i = 0; i < 2; i++) {
          int u = tid + i * 256;
          int an = u >> 2, ap = u & 3;
          *(int4*)&sA[an * 40 + ap * 8] = av[i];
        }
      } else {
#pragma unroll
        for (int i = 0; i < 4; i++) {
          int u = tid + i * 256;
          int xn = u >> 3, xp = u & 7;
          float v[4] = {xv[i].x, xv[i].y, xv[i].z, xv[i].w};
          ushort h[4], l[4];
#pragma unroll
          for (int j = 0; j < 4; j++) {
            uint32 uu = __builtin_bit_cast(uint32, v[j]);
            h[j] = (ushort)(uu >> 16);
            float hf = __builtin_bit_cast(float, uu & 0xffff0000u);
            l[j] = (ushort)(__builtin_bit_cast(uint32, v[j] - hf) >> 16);
          }
          int2 hp = make_int2((int)((uint32)h[0] | ((uint32)h[1] << 16)),
                              (int)((uint32)h[2] | ((uint32)h[3] << 16)));
          int2 lp = make_int2((int)((uint32)l[0] | ((uint32)l[1] << 16)),
                              (int)((uint32)l[2] | ((uint32)l[3] << 16)));
          *(int2*)&sA[xn * 40 + xp * 4] = hp;
          *(int2*)&sA[5120 + xn * 40 + xp * 4] = lp;
        }
      }
      __syncthreads();
      if (ph == 0) {
        bf16x8 a0 = __builtin_bit_cast(bf16x8, *(const int4*)&sA[arow0 * 40 + q * 8]);
        bf16x8 a1 = __builtin_bit_cast(bf16x8, *(const int4*)&sA[arow1 * 40 + q * 8]);
#pragma unroll
        for (int nt = 0; nt < 8; nt++) {
          int nn = nt * 16 + m;
          bf16x8 bh = __builtin_bit_cast(bf16x8, *(const int4*)&sW[nn * 40 + q * 8]);
          bf16x8 bl = __builtin_bit_cast(bf16x8, *(const int4*)&sW[5120 + nn * 40 + q * 8]);
          acc[0][nt] = __builtin_amdgcn_mfma_f32_16x16x32_bf16(a0, bh, acc[0][nt], 0, 0, 0);
          acc[1][nt] = __builtin_amdgcn_mfma_f32_16x16x32_bf16(a1, bh, acc[1][nt], 0, 0, 0);
          acc[0][nt] = __builtin_amdgcn_mfma_f32_16x16x32_bf16(a0, bl, acc[0][nt], 0, 0, 0);
          acc[1][nt] = __builtin_amdgcn_mfma_f32_16x16x32_bf16(a1, bl, acc[1][nt], 0, 0, 0);
        }
      } else {
        bf16x8 ah0 = __builtin_bit_cast(bf16x8, *(const int4*)&sA[arow0 * 40 + q * 8]);
        bf16x8 ah1 = __builtin_bit_cast(bf16x8, *(const int4*)&sA[arow1 * 40 + q * 8]);
        bf16x8 al0 = __builtin_bit_cast(bf16x8, *(const int4*)&sA[5120 + arow0 * 40 + q * 8]);
        bf16x8 al1 = __builtin_bit_cast(bf16x8, *(const int4*)&sA[5120 + arow1 * 40 + q * 8]);
#pragma unroll
        for (int nt = 0; nt < 8; nt++) {
          int nn = nt * 16 + m;
          bf16x8 bh = __builtin_bit_cast(bf16x8, *(const int4*)&sW[nn * 40 + q * 8]);
          bf16x8 bl = __builtin_bit_cast(bf16x8, *(const int4*)&sW[5120 + nn * 40 + q * 8]);
          acc[0][nt] = __builtin_amdgcn_mfma_f32_16x16x32_bf16(ah0, bh, acc[0][nt], 0, 0, 0);
          acc[1][nt] = __builtin_amdgcn_mfma_f32_16x16x32_bf16(ah1, bh, acc[1][nt], 0, 0, 0);
          acc[0][nt] = __builtin_amdgcn_mfma_f32_16x16x32_bf16(ah0, bl, acc[0][nt], 0, 0, 0);
          acc[1][nt] = __builtin_amdgcn_mfma_f32_16x16x32_bf16(ah1, bl, acc[1][nt], 0, 0, 0);
          acc[0][nt] = __builtin_amdgcn_mfma_f32_16x16x32_bf16(al0, bh, acc[0][nt], 0, 0, 0);
          acc[1][nt] = __builtin_amdgcn_mfma_f32_16x16x32_bf16(al1, bh, acc[1][nt], 0, 0, 0);
        }
      }
    }
  }
  __syncthreads();

  float bb[8];
#pragma unroll
  for (int nt = 0; nt < 8; nt++) bb[nt] = bias[nt * 16 + m];

  const int S = 132;
  float* wbuf = (float*)smem + wave * (16 * S);

  int half = lane >> 5;
  int c4 = (lane & 31) * 4;

#pragma unroll
  for (int mt = 0; mt < 2; mt++) {
#pragma unroll
    for (int reg = 0; reg < 4; reg++) {
      float h[8];
      float ss = 0.f;
#pragma unroll
      for (int nt = 0; nt < 8; nt++) {
        float v = acc[mt][nt][reg] + bb[nt];
        if (relu) v = fmaxf(v, 0.f);
        h[nt] = v;
        ss += v * v;
      }
      ss += __shfl_xor(ss, 1);
      ss += __shfl_xor(ss, 2);
      ss += __shfl_xor(ss, 4);
      ss += __shfl_xor(ss, 8);
      float inv = 1.f / fmaxf(sqrtf(ss), EPSN);
      int rrel = q * 4 + reg;
#pragma unroll
      for (int nt = 0; nt < 8; nt++) wbuf[rrel * S + nt * 16 + m] = h[nt] * inv;
    }
#pragma unroll
    for (int i = 0; i < 8; i++) {
      int rrel = i * 2 + half;
      int R = r0g + wave * 32 + mt * 16 + rrel;
      if (R < n) {
        f32x4 hv = *(const f32x4*)&wbuf[rrel * S + c4];
        float4 xr = *(const float4*)&X[(size_t)R * DIM + c4];
        float4 o;
        o.x = hv[0] + xr.x;
        o.y = hv[1] + xr.y;
        o.z = hv[2] + xr.z;
        o.w = hv[3] + xr.w;
        *(float4*)&O[(size_t)R * DIM + c4] = o;
        if (write_bf) {
          int2 pk = make_int2((int)((uint32)rne_bf16(o.x) | ((uint32)rne_bf16(o.y) << 16)),
                              (int)((uint32)rne_bf16(o.z) | ((uint32)rne_bf16(o.w) << 16)));
          *(int2*)&OBF[(size_t)R * DIM + c4] = pk;
        }
      }
    }
  }
}

// ---------------- launch ----------------

extern "C" void kernel_launch(void* const* d_in, const int* in_sizes, int n_in,
                              void* d_out, int out_size, void* d_ws, size_t ws_size,
                              hipStream_t stream) {
  const float* xg0 = (const float*)d_in[0];
  const float* xd0 = (const float*)d_in[1];
  const float* Wl = (const float*)d_in[2];
  const float* Wr = (const float*)d_in[3];
  const float* bs = (const float*)d_in[4];
  const int* src_g2d = (const int*)d_in[5];
  const int* dst_g2d = (const int*)d_in[6];
  const int* src_d2g = (const int*)d_in[7];
  const int* dst_d2g = (const int*)d_in[8];

  float* out_xg = (float*)d_out;
  float* out_xd = (float*)d_out + (size_t)NG * DIM;

  char* p = (char*)d_ws;
  auto alloc = [&](size_t bytes) -> char* {
    char* q = p;
    p += (bytes + 255) & ~(size_t)255;
    return q;
  };
  int* off = (int*)alloc((NTOT + 1) * 4);
  int* csr = (int*)alloc((size_t)2 * NE * 4);
  int* bcnt = (int*)alloc(NBK * 4);
  int* bbase = (int*)alloc((NBK + 1) * 4);
  int* bcur = (int*)alloc(NBK * 4);
  // pairs (12.8 MB, used only during CSR build) aliases agg_bf (38.4 MB, used after)
  char* big = alloc((size_t)NTOT * DIM * 2);
  int2* pairs = (int2*)big;
  ushort* agg_bf = (ushort*)big;
  ushort* xg_bf = (ushort*)alloc((size_t)NG * DIM * 2);
  ushort* xd_bf = (ushort*)alloc((size_t)ND * DIM * 2);
  ushort* WlH = (ushort*)alloc((size_t)4 * 128 * 128 * 2);
  ushort* WlL = (ushort*)alloc((size_t)4 * 128 * 128 * 2);
  ushort* WrH = (ushort*)alloc((size_t)4 * 128 * 128 * 2);
  ushort* WrL = (ushort*)alloc((size_t)4 * 128 * 128 * 2);

  const int TB = 256;

  split_w<<<256, TB, 0, stream>>>(Wl, Wr, WlH, WlL, WrH, WrL);
  to_bf16_all<<<(NTOT * 16 + TB - 1) / TB, TB, 0, stream>>>(xg0, xd0, xg_bf, xd_bf);

  // bucketed CSR build
  zero_ints<<<(NBK + TB - 1) / TB, TB, 0, stream>>>(bcnt, NBK);
  bucket_count<<<256, TB, 0, stream>>>(dst_g2d, dst_d2g, bcnt);
  bucket_scan<<<1, 1024, 0, stream>>>(bcnt, bbase, bcur);
  bucket_scatter<<<SCB, TB, 0, stream>>>(src_g2d, dst_g2d, src_d2g, dst_d2g, bcur, pairs);
  bucket_to_csr<<<NBK, TB, 0, stream>>>(bbase, pairs, off, csr);

  int aggBlocks = NTOT / 4;        // 37500
  int sageBlocks = NBT_D + NBT_G;  // 1173

  // layer 0 (relu); sage also emits bf16 copy of out for layer-1 gather
  agg_comb<<<aggBlocks, TB, 0, stream>>>(xg_bf, xd_bf, off, csr, agg_bf);
  sage_dual<<<sageBlocks, TB, 0, stream>>>(agg_bf, xd0, xg0, WlH, WlL, WrH, WrL, bs, out_xd,
                                           out_xg, xd_bf, xg_bf, 0, 1, 1);

  // layer 1 (no relu), in-place on d_out
  agg_comb<<<aggBlocks, TB, 0, stream>>>(xg_bf, xd_bf, off, csr, agg_bf);
  sage_dual<<<sageBlocks, TB, 0, stream>>>(agg_bf, out_xd, out_xg, WlH, WlL, WrH, WrL, bs,
                                           out_xd, out_xg, xd_bf, xg_bf, 1, 0, 0);
}